// Round 10
// baseline (12550.468 us; speedup 1.0000x reference)
//
#include <hip/hip_runtime.h>

#define F     4096
#define T     2048
#define NBLK  256
#define NTHR  1024

// d_ws layout (NOTHING is memset):
//   [0, 1024)             : tagboard[256] u32 — board[b] >= t (signed-diff,
//                           wraparound-safe) means block b published step t-1.
//                           0xAA poison (0xAAAAAAAA) reads as NEGATIVE diff
//                           vs tags 1..2049 -> "not ready". Monotone stores only.
//   [4096, 4096 + K*F*8)  : ring[K][4096] of {f32 val, u32 tag} pairs; tag
//                           exact-equality per pair (poison never matches, and
//                           the producer's store WILL arrive -> retry is live).
// K chosen at launch from ws_size (power of 2, 4..256).

typedef unsigned long long u64;
typedef unsigned int u32;

template <int CTRL>
__device__ __forceinline__ float dpp_add(float x) {
    int xi = __builtin_bit_cast(int, x);
    int yi = __builtin_amdgcn_update_dpp(0, xi, CTRL, 0xf, 0xf, false);
    return x + __builtin_bit_cast(float, yi);
}

// Full wave64 sum; total lands in lane 63. VALU-only.
__device__ __forceinline__ float wave_sum(float x) {
    x = dpp_add<0x111>(x); // row_shr:1
    x = dpp_add<0x112>(x); // row_shr:2
    x = dpp_add<0x114>(x); // row_shr:4
    x = dpp_add<0x118>(x); // row_shr:8
    x = dpp_add<0x142>(x); // row_bcast:15
    x = dpp_add<0x143>(x); // row_bcast:31
    return x;
}

#define PIN4(v) asm volatile("" : "+v"((v).x), "+v"((v).y), "+v"((v).z), "+v"((v).w))

__device__ __forceinline__ u64 cload_u64(const u64* p) {
    return __hip_atomic_load(p, __ATOMIC_RELAXED, __HIP_MEMORY_SCOPE_AGENT);
}
__device__ __forceinline__ void cstore_u64(u64* p, u64 v) {
    __hip_atomic_store(p, v, __ATOMIC_RELAXED, __HIP_MEMORY_SCOPE_AGENT);
}
__device__ __forceinline__ u32 cload_u32(const u32* p) {
    return __hip_atomic_load(p, __ATOMIC_RELAXED, __HIP_MEMORY_SCOPE_AGENT);
}
__device__ __forceinline__ void cstore_u32(u32* p, u32 v) {
    __hip_atomic_store(p, v, __ATOMIC_RELAXED, __HIP_MEMORY_SCOPE_AGENT);
}

// wraparound/poison-safe "board has reached tag" check
__device__ __forceinline__ bool reached(u32 c, u32 tag) {
    return (int)(c - tag) >= 0;
}

__global__ __launch_bounds__(NTHR, 4) void rc_kernel(
    const float* __restrict__ x, const float* __restrict__ Wres,
    const float* __restrict__ wout, float* __restrict__ out,
    u32* __restrict__ tagboard, u64* __restrict__ ring, u32 kmask)
{
    __shared__ __align__(16) float fl[F];     // staged feats vector (16 KB)
    __shared__ float red[2][16][4];           // double-buffered matvec partials
    __shared__ float redo[2][16];             // double-buffered readout partials

    const int tid  = threadIdx.x;
    const int b    = blockIdx.x;
    const int w    = tid >> 6;
    const int lane = tid & 63;
    const int wr   = w & 3;   // row-group (4 rows each)
    const int wk   = w >> 2;  // k-group (1024 k each)

    // ---- persistent W_res fragment: 4 rows x 16 k = 64 fp32 regs/lane ----
    const int row0 = b * 16 + wr * 4;
    const int kofs = wk * 1024 + lane * 4;
    float4 wreg[4][4];
#pragma unroll
    for (int j = 0; j < 4; ++j) {
        const float* wp = Wres + (size_t)(row0 + j) * F + kofs;
#pragma unroll
        for (int i = 0; i < 4; ++i)
            wreg[j][i] = *(const float4*)(wp + i * 256);
    }
#pragma unroll
    for (int j = 0; j < 4; ++j) {
        PIN4(wreg[j][0]); PIN4(wreg[j][1]); PIN4(wreg[j][2]); PIN4(wreg[j][3]);
    }

    // ---- persistent w_out fragment (fused readout): 8 fp32 regs/lane ----
    const int rrow = b * 2 + (wr & 1);
    const int i0   = (wr >> 1) * 2;
    const float* wop = wout + (size_t)rrow * F + kofs + i0 * 256;
    float4 wo0 = *(const float4*)(wop);
    float4 wo1 = *(const float4*)(wop + 256);
    PIN4(wo0); PIN4(wo1);

    // ---- x prefetch for step 0 ----
    float xval = 0.f;
    if (tid < 16) xval = x[(size_t)(b * 16 + tid) * T + 0];

    const int ep = w * 256 + lane * 4;  // this lane's chunk base (elements)

    for (int t = 0; t <= T; ++t) {
        // ---- 1. detect: wave 0 polls tagboard, predicated monotone retry ----
        if (t > 0 && w == 0) {
            const u32 tag = (u32)t;
            const u32* tb = tagboard + lane * 4;
            u32 c0 = cload_u32(tb + 0), c1 = cload_u32(tb + 1);
            u32 c2 = cload_u32(tb + 2), c3 = cload_u32(tb + 3);
            bool ok0 = reached(c0, tag), ok1 = reached(c1, tag);
            bool ok2 = reached(c2, tag), ok3 = reached(c3, tag);
            while (!__all(ok0 & ok1 & ok2 & ok3)) {
                __builtin_amdgcn_s_sleep(1);
                if (!ok0) { c0 = cload_u32(tb + 0); ok0 = reached(c0, tag); }
                if (!ok1) { c1 = cload_u32(tb + 1); ok1 = reached(c1, tag); }
                if (!ok2) { c2 = cload_u32(tb + 2); ok2 = reached(c2, tag); }
                if (!ok3) { c3 = cload_u32(tb + 3); ok3 = reached(c3, tag); }
            }
        }
        __syncthreads();  // (G) all producers have committed step t-1 data

        // ---- 2. bulk CACHED read (L2-dedup per XCD) + tag validation ----
        if (t > 0) {
            const u64* rs = ring + (size_t)((t - 1) & kmask) * F + ep;
            const u32 tag = (u32)t;
            asm volatile("" ::: "memory");  // no hoisting above the detect
            uint4 q0 = *(const uint4*)(rs);       // pairs 0,1 (16 B)
            uint4 q1 = *(const uint4*)(rs + 2);   // pairs 2,3 (16 B)
            u64 p0 = ((u64)q0.y << 32) | (u64)q0.x;
            u64 p1 = ((u64)q0.w << 32) | (u64)q0.z;
            u64 p2 = ((u64)q1.y << 32) | (u64)q1.x;
            u64 p3 = ((u64)q1.w << 32) | (u64)q1.z;
            bool ok0 = ((u32)(p0 >> 32) == tag), ok1 = ((u32)(p1 >> 32) == tag);
            bool ok2 = ((u32)(p2 >> 32) == tag), ok3 = ((u32)(p3 >> 32) == tag);
            // stale cached line (ring wrap/race) -> predicated sc1 retry; live
            // because the producer's coherent store has already been issued.
            while (!__all(ok0 & ok1 & ok2 & ok3)) {
                __builtin_amdgcn_s_sleep(1);
                if (!ok0) { p0 = cload_u64(rs + 0); ok0 = ((u32)(p0 >> 32) == tag); }
                if (!ok1) { p1 = cload_u64(rs + 1); ok1 = ((u32)(p1 >> 32) == tag); }
                if (!ok2) { p2 = cload_u64(rs + 2); ok2 = ((u32)(p2 >> 32) == tag); }
                if (!ok3) { p3 = cload_u64(rs + 3); ok3 = ((u32)(p3 >> 32) == tag); }
            }
            float4 v;
            v.x = __builtin_bit_cast(float, (u32)p0);
            v.y = __builtin_bit_cast(float, (u32)p1);
            v.z = __builtin_bit_cast(float, (u32)p2);
            v.w = __builtin_bit_cast(float, (u32)p3);
            *(float4*)&fl[ep] = v;
        } else {
            *(float4*)&fl[ep] = make_float4(0.f, 0.f, 0.f, 0.f);  // feats_{-1}=0
        }
        __syncthreads();  // (L) feats staged

        // ---- 3. matvec from LDS + fused readout partial ----
        float4 f0 = *(const float4*)&fl[kofs + 0 * 256];
        float4 f1 = *(const float4*)&fl[kofs + 1 * 256];
        float4 f2 = *(const float4*)&fl[kofs + 2 * 256];
        float4 f3 = *(const float4*)&fl[kofs + 3 * 256];

        float acc0 = 0.f, acc1 = 0.f, acc2 = 0.f, acc3 = 0.f;
#define DOT_STEP(i, fv) \
        acc0 += wreg[0][i].x * fv.x + wreg[0][i].y * fv.y + wreg[0][i].z * fv.z + wreg[0][i].w * fv.w; \
        acc1 += wreg[1][i].x * fv.x + wreg[1][i].y * fv.y + wreg[1][i].z * fv.z + wreg[1][i].w * fv.w; \
        acc2 += wreg[2][i].x * fv.x + wreg[2][i].y * fv.y + wreg[2][i].z * fv.z + wreg[2][i].w * fv.w; \
        acc3 += wreg[3][i].x * fv.x + wreg[3][i].y * fv.y + wreg[3][i].z * fv.z + wreg[3][i].w * fv.w;
        DOT_STEP(0, f0)
        DOT_STEP(1, f1)
        DOT_STEP(2, f2)
        DOT_STEP(3, f3)
#undef DOT_STEP

        float4 ra, rb;
        if (i0 == 0) { ra = f0; rb = f1; } else { ra = f2; rb = f3; }
        float p = wo0.x * ra.x + wo0.y * ra.y + wo0.z * ra.z + wo0.w * ra.w
                + wo1.x * rb.x + wo1.y * rb.y + wo1.z * rb.z + wo1.w * rb.w;

        // ---- 4. wave reduce, lane63 -> LDS (double-buffered by t&1) ----
        acc0 = wave_sum(acc0);
        acc1 = wave_sum(acc1);
        acc2 = wave_sum(acc2);
        acc3 = wave_sum(acc3);
        p    = wave_sum(p);
        const int pb = t & 1;
        if (lane == 63) {
            red[pb][w][0] = acc0; red[pb][w][1] = acc1;
            red[pb][w][2] = acc2; red[pb][w][3] = acc3;
            redo[pb][w] = p;
        }
        __syncthreads();  // (A)

        // ---- 5. wave 0: combine, clamp, publish tagged, signal tagboard ----
        if (w == 0 && t < T) {
            if (lane < 16) {
                const int r = lane, rw = r >> 2, rj = r & 3;
                float s = red[pb][rw][rj] + red[pb][rw + 4][rj]
                        + red[pb][rw + 8][rj] + red[pb][rw + 12][rj];
                s += xval;
                s = fminf(1.f, fmaxf(-1.f, s));
                u64 pk = ((u64)(u32)(t + 1) << 32) | (u64)__builtin_bit_cast(u32, s);
                cstore_u64(ring + (size_t)(t & kmask) * F + b * 16 + r, pk);
            }
            // data at coherence point, THEN the tagboard store (plain, no RMW)
            asm volatile("s_waitcnt vmcnt(0)" ::: "memory");
            if (lane == 0)
                cstore_u32(tagboard + b, (u32)(t + 1));
            if (lane < 16) {
                const int tn = (t + 1 < T) ? (t + 1) : (T - 1);
                xval = x[(size_t)(b * 16 + lane) * T + tn];  // off critical path
            }
        }

        // ---- 6. out[:, t-1] store (wave 1; off the publish path) ----
        if (t > 0 && tid >= 64 && tid < 66) {
            const int r = tid - 64;
            float s = redo[pb][r]      + redo[pb][r + 2]  + redo[pb][r + 4]
                    + redo[pb][r + 6]  + redo[pb][r + 8]  + redo[pb][r + 10]
                    + redo[pb][r + 12] + redo[pb][r + 14];
            out[(size_t)(b * 2 + r) * T + (t - 1)] = s;
        }
        // red/redo double-buffered; fl rewrite at t+1 fenced by (G)/(L); ring
        // slot reuse safe (K>=4): publishing step t requires detect of step
        // t-1 across ALL blocks, so inter-block skew < 2 steps.
    }
}

extern "C" void kernel_launch(void* const* d_in, const int* in_sizes, int n_in,
                              void* d_out, int out_size, void* d_ws, size_t ws_size,
                              hipStream_t stream) {
    const float* x    = (const float*)d_in[0];
    const float* Wres = (const float*)d_in[1];
    const float* wout = (const float*)d_in[2];
    float* out        = (float*)d_out;
    u32* tagboard     = (u32*)d_ws;
    u64* ring         = (u64*)((char*)d_ws + 4096);

    // adaptive ring size: largest power-of-2 slots fitting ws (4..256).
    size_t avail = (ws_size > 4096) ? (ws_size - 4096) : 0;
    u32 kslots = 4;
    while (kslots < 256 && (size_t)(kslots * 2) * F * 8ull <= avail) kslots *= 2;
    u32 kmask = kslots - 1;

    // no memset needed: tagboard uses signed-diff monotone checks (0xAA poison
    // reads "not ready"); ring tags use exact equality (poison never matches).

    void* args[] = { (void*)&x, (void*)&Wres, (void*)&wout, (void*)&out,
                     (void*)&tagboard, (void*)&ring, (void*)&kmask };
    (void)hipLaunchCooperativeKernel((const void*)rc_kernel, dim3(NBLK), dim3(NTHR),
                                     args, 0, stream);
}

// Round 11
// 6969.118 us; speedup vs baseline: 1.8009x; 1.8009x over previous
//
#include <hip/hip_runtime.h>

#define F     4096
#define T     2048
#define NBLK  256
#define NTHR  1024
#define K     4      // ring slots; lockstep bounds skew so K>=2 is safe

// d_ws layout (NOTHING memset; harness re-poisons d_ws to 0xAA each launch):
//   [4096, 4096 + K*F*4) : ring[K][4096] u32 pairs {tag u16 << 16 | f16 bits}.
//   Poison 0xAAAAAAAA -> tag 0xAAAA = 43690, never equals a real tag (1..2049).
//   Data IS the flag: a pair is valid iff its tag matches; producer stores are
//   fire-and-forget; consumers accept fresh chunks immediately (overlapped).

typedef unsigned long long u64;
typedef unsigned int u32;
typedef unsigned short u16;

template <int CTRL>
__device__ __forceinline__ float dpp_add(float x) {
    int xi = __builtin_bit_cast(int, x);
    int yi = __builtin_amdgcn_update_dpp(0, xi, CTRL, 0xf, 0xf, false);
    return x + __builtin_bit_cast(float, yi);
}

// Full wave64 sum; total lands in lane 63. VALU-only.
__device__ __forceinline__ float wave_sum(float x) {
    x = dpp_add<0x111>(x); // row_shr:1
    x = dpp_add<0x112>(x); // row_shr:2
    x = dpp_add<0x114>(x); // row_shr:4
    x = dpp_add<0x118>(x); // row_shr:8
    x = dpp_add<0x142>(x); // row_bcast:15
    x = dpp_add<0x143>(x); // row_bcast:31
    return x;
}

#define PIN4(v) asm volatile("" : "+v"((v).x), "+v"((v).y), "+v"((v).z), "+v"((v).w))

__device__ __forceinline__ u64 cload_u64(const u64* p) {
    return __hip_atomic_load(p, __ATOMIC_RELAXED, __HIP_MEMORY_SCOPE_AGENT);
}
__device__ __forceinline__ void cstore_u32(u32* p, u32 v) {
    __hip_atomic_store(p, v, __ATOMIC_RELAXED, __HIP_MEMORY_SCOPE_AGENT);
}

__device__ __forceinline__ float half_to_f(u32 bits) {
    return (float)__builtin_bit_cast(_Float16, (u16)(bits & 0xffffu));
}

__global__ __launch_bounds__(NTHR, 4) void rc_kernel(
    const float* __restrict__ x, const float* __restrict__ Wres,
    const float* __restrict__ wout, float* __restrict__ out,
    u32* __restrict__ ring)
{
    __shared__ __align__(16) float fl[F];     // staged feats vector (16 KB)
    __shared__ float red[2][16][4];           // double-buffered matvec partials
    __shared__ float redo[2][16];             // double-buffered readout partials

    const int tid  = threadIdx.x;
    const int b    = blockIdx.x;
    const int w    = tid >> 6;
    const int lane = tid & 63;
    const int wr   = w & 3;   // row-group (4 rows each)
    const int wk   = w >> 2;  // k-group (1024 k each)

    // ---- persistent W_res fragment: 4 rows x 16 k = 64 fp32 regs/lane ----
    const int row0 = b * 16 + wr * 4;
    const int kofs = wk * 1024 + lane * 4;
    float4 wreg[4][4];
#pragma unroll
    for (int j = 0; j < 4; ++j) {
        const float* wp = Wres + (size_t)(row0 + j) * F + kofs;
#pragma unroll
        for (int i = 0; i < 4; ++i)
            wreg[j][i] = *(const float4*)(wp + i * 256);
    }
#pragma unroll
    for (int j = 0; j < 4; ++j) {
        PIN4(wreg[j][0]); PIN4(wreg[j][1]); PIN4(wreg[j][2]); PIN4(wreg[j][3]);
    }

    // ---- persistent w_out fragment (fused readout): 8 fp32 regs/lane ----
    const int rrow = b * 2 + (wr & 1);
    const int i0   = (wr >> 1) * 2;
    const float* wop = wout + (size_t)rrow * F + kofs + i0 * 256;
    float4 wo0 = *(const float4*)(wop);
    float4 wo1 = *(const float4*)(wop + 256);
    PIN4(wo0); PIN4(wo1);

    // ---- x prefetch for step 0 ----
    float xval = 0.f;
    if (tid < 16) xval = x[(size_t)(b * 16 + tid) * T + 0];

    const int ep = w * 256 + lane * 4;  // this lane's chunk base (elements)

    for (int t = 0; t <= T; ++t) {
        // ---- 1. poll feats_{t-1} pairs (data-as-flag) and stage to LDS ----
        if (t > 0) {
            const u32* rs = ring + (size_t)((t - 1) & (K - 1)) * F + ep;
            const u32 tag = (u32)t;
            // two u64 loads = 4 packed pairs {tag16|f16}
            u64 p01 = cload_u64((const u64*)rs);
            u64 p23 = cload_u64((const u64*)(rs + 2));
            bool okA = ((u32)(p01 & 0xffffffffu) >> 16 == tag)
                     & ((u32)(p01 >> 32) >> 16 == tag);
            bool okB = ((u32)(p23 & 0xffffffffu) >> 16 == tag)
                     & ((u32)(p23 >> 32) >> 16 == tag);
            while (!__all(okA & okB)) {
                __builtin_amdgcn_s_sleep(1);
                if (!okA) {
                    p01 = cload_u64((const u64*)rs);
                    okA = ((u32)(p01 & 0xffffffffu) >> 16 == tag)
                        & ((u32)(p01 >> 32) >> 16 == tag);
                }
                if (!okB) {
                    p23 = cload_u64((const u64*)(rs + 2));
                    okB = ((u32)(p23 & 0xffffffffu) >> 16 == tag)
                        & ((u32)(p23 >> 32) >> 16 == tag);
                }
            }
            float4 v;
            v.x = half_to_f((u32)(p01 & 0xffffffffu));
            v.y = half_to_f((u32)(p01 >> 32));
            v.z = half_to_f((u32)(p23 & 0xffffffffu));
            v.w = half_to_f((u32)(p23 >> 32));
            *(float4*)&fl[ep] = v;
        } else {
            *(float4*)&fl[ep] = make_float4(0.f, 0.f, 0.f, 0.f);  // feats_{-1}=0
        }
        __syncthreads();  // (L) feats staged

        // ---- 2. matvec from LDS + fused readout partial ----
        float4 f0 = *(const float4*)&fl[kofs + 0 * 256];
        float4 f1 = *(const float4*)&fl[kofs + 1 * 256];
        float4 f2 = *(const float4*)&fl[kofs + 2 * 256];
        float4 f3 = *(const float4*)&fl[kofs + 3 * 256];

        float acc0 = 0.f, acc1 = 0.f, acc2 = 0.f, acc3 = 0.f;
#define DOT_STEP(i, fv) \
        acc0 += wreg[0][i].x * fv.x + wreg[0][i].y * fv.y + wreg[0][i].z * fv.z + wreg[0][i].w * fv.w; \
        acc1 += wreg[1][i].x * fv.x + wreg[1][i].y * fv.y + wreg[1][i].z * fv.z + wreg[1][i].w * fv.w; \
        acc2 += wreg[2][i].x * fv.x + wreg[2][i].y * fv.y + wreg[2][i].z * fv.z + wreg[2][i].w * fv.w; \
        acc3 += wreg[3][i].x * fv.x + wreg[3][i].y * fv.y + wreg[3][i].z * fv.z + wreg[3][i].w * fv.w;
        DOT_STEP(0, f0)
        DOT_STEP(1, f1)
        DOT_STEP(2, f2)
        DOT_STEP(3, f3)
#undef DOT_STEP

        float4 ra, rb;
        if (i0 == 0) { ra = f0; rb = f1; } else { ra = f2; rb = f3; }
        float p = wo0.x * ra.x + wo0.y * ra.y + wo0.z * ra.z + wo0.w * ra.w
                + wo1.x * rb.x + wo1.y * rb.y + wo1.z * rb.z + wo1.w * rb.w;

        // ---- 3. wave reduce, lane63 -> LDS (double-buffered by t&1) ----
        acc0 = wave_sum(acc0);
        acc1 = wave_sum(acc1);
        acc2 = wave_sum(acc2);
        acc3 = wave_sum(acc3);
        p    = wave_sum(p);
        const int pb = t & 1;
        if (lane == 63) {
            red[pb][w][0] = acc0; red[pb][w][1] = acc1;
            red[pb][w][2] = acc2; red[pb][w][3] = acc3;
            redo[pb][w] = p;
        }
        __syncthreads();  // (A)

        // ---- 4. wave 0: combine, clamp, publish packed pair (store = flag) ----
        if (w == 0 && t < T) {
            if (lane < 16) {
                const int r = lane, rw = r >> 2, rj = r & 3;
                float s = red[pb][rw][rj] + red[pb][rw + 4][rj]
                        + red[pb][rw + 8][rj] + red[pb][rw + 12][rj];
                s += xval;
                s = fminf(1.f, fmaxf(-1.f, s));
                u32 hb = (u32)__builtin_bit_cast(u16, (_Float16)s);
                u32 pk = ((u32)(t + 1) << 16) | hb;
                cstore_u32(ring + (size_t)(t & (K - 1)) * F + b * 16 + r, pk);
                const int tn = (t + 1 < T) ? (t + 1) : (T - 1);
                xval = x[(size_t)(b * 16 + lane) * T + tn];  // off critical path
            }
        }

        // ---- 5. out[:, t-1] store (wave 1; off the publish path) ----
        if (t > 0 && tid >= 64 && tid < 66) {
            const int r = tid - 64;
            float s = redo[pb][r]      + redo[pb][r + 2]  + redo[pb][r + 4]
                    + redo[pb][r + 6]  + redo[pb][r + 8]  + redo[pb][r + 10]
                    + redo[pb][r + 12] + redo[pb][r + 14];
            out[(size_t)(b * 2 + r) * T + (t - 1)] = s;
        }
        // red/redo double-buffered; fl rewrite at t+1 separated by sync (A);
        // ring slot reuse: block publishes step t only after ALL blocks
        // published t-1 (lockstep), so oldest in-flight reads are step t-1
        // -> K>=2 safe, K=4 used. No capacity counters needed.
    }
}

extern "C" void kernel_launch(void* const* d_in, const int* in_sizes, int n_in,
                              void* d_out, int out_size, void* d_ws, size_t ws_size,
                              hipStream_t stream) {
    const float* x    = (const float*)d_in[0];
    const float* Wres = (const float*)d_in[1];
    const float* wout = (const float*)d_in[2];
    float* out        = (float*)d_out;
    u32* ring         = (u32*)((char*)d_ws + 4096);

    // no memset: ring tags are self-describing; 0xAA poison never matches.

    void* args[] = { (void*)&x, (void*)&Wres, (void*)&wout, (void*)&out,
                     (void*)&ring };
    (void)hipLaunchCooperativeKernel((const void*)rc_kernel, dim3(NBLK), dim3(NTHR),
                                     args, 0, stream);
}